// Round 18
// baseline (130.842 us; speedup 1.0000x reference)
//
#include <hip/hip_runtime.h>
#include <hip/hip_bf16.h>
#include <stdint.h>

#define HIDDEN 1024
#define NHEADS 16
#define DHEAD  64
#define BATCH  2
#define SEQ    2048
#define MROWS  (BATCH*SEQ)   // 4096
#define QKVC   (3*HIDDEN)    // 3072

typedef unsigned short u16;
typedef unsigned int   u32;
typedef __bf16 bf16x8 __attribute__((ext_vector_type(8)));
typedef __bf16 bf16x2 __attribute__((ext_vector_type(2)));
typedef float  f32x4  __attribute__((ext_vector_type(4)));
typedef float  f32x16 __attribute__((ext_vector_type(16)));
typedef short  s16x4  __attribute__((ext_vector_type(4)));
typedef u16    u16x8  __attribute__((ext_vector_type(8)));
typedef u32    u32x2  __attribute__((ext_vector_type(2)));

typedef const __attribute__((address_space(1))) void gvoid_t;
typedef       __attribute__((address_space(3))) void lvoid_t;

__device__ __forceinline__ gvoid_t* to_glob(const void* p){
  return (gvoid_t*)(uintptr_t)p;
}
__device__ __forceinline__ lvoid_t* to_lds(void* p){
  return (lvoid_t*)(uintptr_t)p;
}
__device__ __forceinline__ u32 lds_off(const void* p){
  return (u32)(uintptr_t)p;
}

// native f32->bf16 (hardware RNE cvt on gfx950)
__device__ __forceinline__ u16 f2bf(float x){
  __bf16 h = (__bf16)x;
  return __builtin_bit_cast(u16, h);
}
// packed f32x2 -> bf16x2 word (compiler emits v_cvt_pk_bf16_f32)
__device__ __forceinline__ u32 pk2(float a, float b){
  bf16x2 t = { (__bf16)a, (__bf16)b };
  return __builtin_bit_cast(u32, t);
}

#define MFMA32(a, b, c) __builtin_amdgcn_mfma_f32_32x32x16_bf16(a, b, c, 0, 0, 0)

// ---------------- fp32 -> bf16 conversion, all 3 inputs in one launch ----------------
#define CVT_N0 1048576   // enc      (4M f32 / 4)
#define CVT_N1  786432   // attn_w   (3M f32 / 4)
#define CVT_N2  262144   // out_w    (1M f32 / 4)
__global__ __launch_bounds__(256) void k_cvt3(const float* __restrict__ e,
                                              const float* __restrict__ wa,
                                              const float* __restrict__ wo,
                                              u16* __restrict__ eb,
                                              u16* __restrict__ wab,
                                              u16* __restrict__ wob){
  int i = blockIdx.x * 256 + threadIdx.x;
  const float* src; u16* dst;
  if (i < CVT_N0){ src = e; dst = eb; }
  else if (i < CVT_N0 + CVT_N1){ i -= CVT_N0; src = wa; dst = wab; }
  else if (i < CVT_N0 + CVT_N1 + CVT_N2){ i -= CVT_N0 + CVT_N1; src = wo; dst = wob; }
  else return;
  const float4 v = reinterpret_cast<const float4*>(src)[i];
  ushort4 o;
  o.x = f2bf(v.x); o.y = f2bf(v.y); o.z = f2bf(v.z); o.w = f2bf(v.w);
  reinterpret_cast<ushort4*>(dst)[i] = o;
}

// ---------------- bf16 GEMM, C = A * B^T + bias (R14 verified: T1 swizzle) ----------------
template<int NC, bool BF16OUT>
__global__ __launch_bounds__(256) void k_gemm(const u16* __restrict__ A,
                                              const u16* __restrict__ B,
                                              const float* __restrict__ bias,
                                              void* __restrict__ C){
  constexpr int K = HIDDEN;
  __shared__ u16 As[2][128*32];
  __shared__ u16 Bs[2][128*32];
  const int lin = blockIdx.x + gridDim.x * blockIdx.y;
  const int xcd = lin & 7;
  const int pos = lin >> 3;
  const int mt  = pos & 31;                 // gridDim.x == 32 always here
  const int nt  = xcd * (gridDim.y >> 3) + (pos >> 5);
  const int m0 = mt * 128;
  const int n0 = nt * 128;
  const int tid = threadIdx.x;
  const int w = tid >> 6, l = tid & 63;
  const int wr = w >> 1, wc = w & 1;

  const f32x4 fz = {0.f, 0.f, 0.f, 0.f};
  f32x4 acc[4][4];
  #pragma unroll
  for (int i = 0; i < 4; ++i)
    #pragma unroll
    for (int j = 0; j < 4; ++j) acc[i][j] = fz;

  const u16* ap = A + (size_t)(m0 + (tid >> 2)) * K + (tid & 3) * 8;
  const u16* bp = B + (size_t)(n0 + (tid >> 2)) * K + (tid & 3) * 8;

  auto stage = [&](int k0, int buf){
    __builtin_amdgcn_global_load_lds(to_glob(ap + k0),        to_lds(&As[buf][w*512]),        16, 0, 0);
    __builtin_amdgcn_global_load_lds(to_glob(ap + 64*K + k0), to_lds(&As[buf][2048 + w*512]), 16, 0, 0);
    __builtin_amdgcn_global_load_lds(to_glob(bp + k0),        to_lds(&Bs[buf][w*512]),        16, 0, 0);
    __builtin_amdgcn_global_load_lds(to_glob(bp + 64*K + k0), to_lds(&Bs[buf][2048 + w*512]), 16, 0, 0);
  };

  stage(0, 0);
  __syncthreads();

  for (int k0 = 0; k0 < K; k0 += 32){
    const int cur = (k0 >> 5) & 1;
    if (k0 + 32 < K) stage(k0 + 32, cur ^ 1);

    bf16x8 af[4], bfr[4];
    #pragma unroll
    for (int mf = 0; mf < 4; ++mf)
      af[mf]  = *(const bf16x8*)&As[cur][(wr*64 + mf*16 + (l & 15))*32 + (l >> 4)*8];
    #pragma unroll
    for (int nf = 0; nf < 4; ++nf)
      bfr[nf] = *(const bf16x8*)&Bs[cur][(wc*64 + nf*16 + (l & 15))*32 + (l >> 4)*8];
    #pragma unroll
    for (int mf = 0; mf < 4; ++mf)
      #pragma unroll
      for (int nf = 0; nf < 4; ++nf)
        acc[mf][nf] = __builtin_amdgcn_mfma_f32_16x16x32_bf16(af[mf], bfr[nf], acc[mf][nf], 0, 0, 0);

    __syncthreads();
  }

  #pragma unroll
  for (int nf = 0; nf < 4; ++nf){
    const int col = n0 + wc*64 + nf*16 + (l & 15);
    const float bv = bias[col];
    #pragma unroll
    for (int mf = 0; mf < 4; ++mf){
      #pragma unroll
      for (int r = 0; r < 4; ++r){
        const int row = m0 + wr*64 + mf*16 + (l >> 4)*4 + r;
        const float v = acc[mf][nf][r] + bv;
        if constexpr (BF16OUT) ((u16*)C)[(size_t)row * NC + col] = f2bf(v);
        else                   ((float*)C)[(size_t)row * NC + col] = v;
      }
    }
  }
}

// ---------------- causal flash attention: paired-equal blocks + helper waves ----
// grid = (32 bh, 16 p), block 512 = 8 waves. Block owns q-groups {A=p, B=31-p}.
// Wave w: hr=w&1 (k-half), wr=(w>>1)&1 (q-sub), gp=w>>2 (0=A,1=B). All waves run
// exactly 17 trips: B-waves do the first 17 units of their half; A-waves do
// their p+1 units then HELP with the last 15-p units of the same-half B range
// (A-state stashed to cold regs at the switch; Q reloaded w/ one vmcnt(0)
// drain). 512 blocks x 2/CU (80 KiB LDS) = 16 waves/CU FLAT — fixes the
// all-resident decay (~9.5 waves avg) that capped R8..R17 at ~46us.
// Staging: 4 domains = (gp,hr) wave-pairs, each with the R14-verified
// K 3-buf / V 2-buf vmcnt(2) ledger. End: 2-phase LDS merge (A 2-way, B 4-way).
__global__ __launch_bounds__(512, 4) void k_attn(const u16* __restrict__ qkv,
                                                 u16* __restrict__ aout){
  __shared__ u16 smem[40960];   // 80 KiB: domain d at [d*10240]: K 3x2048 | V 2x2048 (u16)

  const int bh = blockIdx.x;
  const int b  = bh >> 4;
  const int h  = bh & 15;
  const int p  = blockIdx.y;               // 0..15
  const int gA = p, gB = 31 - p;
  const int tid = threadIdx.x;
  const int l  = tid & 63;
  const int w  = tid >> 6;                 // 0..7
  const int hr = w & 1;                    // k-half
  const int wr = (w >> 1) & 1;             // q-sub (also wave-within-domain)
  const int gp = w >> 2;                   // 0 = group A, 1 = group B
  const int dom = gp*2 + hr;               // staging domain 0..3
  const int dlane = wr*64 + l;             // lane within domain (0..127)
  const int UA = p + 1, UB = 32 - p;       // per-half unit counts
  const int kbA = hr * UA, kbB = hr * UB;  // half base (units of 32 k-rows)
  const size_t base = (size_t)b * SEQ * QKVC + (size_t)h * 192;
  const float CEXP = 0.18033688011112042f; // 0.125 * log2(e)

  u16* const Kreg = smem + dom*10240;          // + cb*2048, cb in {0,1,2}
  u16* const Vreg = smem + dom*10240 + 6144;   // + vb*2048, vb in {0,1}

  // ---- per-lane staging source bases (XOR pre-swizzled K; inverse-subtile V)
  const int cgK = (dlane & 7) ^ ((dlane >> 3) & 7);
  const u16* const baseK = qkv + base + (size_t)(dlane >> 3) * QKVC + 64 + cgK * 8;
  const int vk = ((dlane >> 5) << 2) | ((dlane >> 1) & 3);
  const int vd = (((dlane >> 3) & 3) << 4) | ((dlane & 1) << 3);
  const u16* const baseV = qkv + base + (size_t)vk * QKVC + 128 + vd;

  auto stageK = [&](int u, int cb){   // 2 vmem instrs per wave
    const u16* pk = baseK + (size_t)u * 32 * QKVC;
    #pragma unroll
    for (int t = 0; t < 2; ++t)
      __builtin_amdgcn_global_load_lds(to_glob(pk + t*16*QKVC),
                                       to_lds(&Kreg[cb*2048 + t*1024 + wr*512]), 16, 0, 0);
  };
  auto stageV = [&](int u, int vb){   // 2 vmem instrs per wave
    const u16* pv = baseV + (size_t)u * 32 * QKVC;
    #pragma unroll
    for (int t = 0; t < 2; ++t)
      __builtin_amdgcn_global_load_lds(to_glob(pv + t*16*QKVC),
                                       to_lds(&Vreg[vb*2048 + t*1024 + wr*512]), 16, 0, 0);
  };

  // trip t (0..16) -> unit index within the group's k-range (clamped for
  // staging lookahead / idle restages; sequences identical across a domain)
  auto unit_of = [&](int t)->int{
    if (t > 16) t = 16;
    if (gp) return kbB + t;                       // B: 17 own units (t<=16<=UB-1)
    if (t <= p) return kbA + t;                   // A own (p+1 units)
    int uu = kbB + 17 + (t - p - 1);              // helper: B tail
    const int um = kbB + UB - 1;
    return uu > um ? um : uu;
  };

  // Q B-frags for current state: col=q=(l&31), k-dim=d=(l>>5)*8 + dd*16 + j
  int q0s = (gp ? gB : gA)*64 + wr*32;
  bf16x8 qf[4];
  {
    const u16* qp = qkv + base + (size_t)(q0s + (l & 31)) * QKVC + (l >> 5) * 8;
    #pragma unroll
    for (int dd = 0; dd < 4; ++dd) qf[dd] = *(const bf16x8*)(qp + dd*16);
  }

  f32x16 o0{}, o1{};              // O[q=row(r)][d=(l&31)+{0,32}]
  float m = -1e30f, lsum = 0.f;
  f32x16 so0{}, so1{};            // stash for A-state (cold; A-waves only)
  float sm = -1e30f, sl = 0.f;

  // prologue ledger: K0, V0, K1 (6 ops outstanding; qf loads ahead of them)
  stageK(unit_of(0), 0);
  stageV(unit_of(0), 0);
  stageK(unit_of(1), 1);

  const u32 vbytes = lds_off(Vreg) + (l & 15)*8 + ((l >> 4) & 1)*128 + (l >> 5)*1024;

  int cb3 = 0, vb2 = 0;
  for (int t = 0; t < 17; ++t){
    // own K(t)+V(t) landed (K(t+1) stays in flight); align waves, NO drain
    asm volatile("s_waitcnt vmcnt(2)" ::: "memory");
    __builtin_amdgcn_sched_barrier(0);
    __builtin_amdgcn_s_barrier();
    __builtin_amdgcn_sched_barrier(0);

    // V before K (keeps the two unwaited ops == next-K); clamped at tail
    stageV(unit_of(t + 1), vb2 ^ 1);
    stageK(unit_of(t + 2), cb3 == 0 ? 2 : cb3 - 1);

    // ---- A-waves: switch A -> helper(B) state once
    if (gp == 0 && t == p + 1){
      lsum += __shfl(lsum, l ^ 32);          // finalize A half-sum
      sm = m; sl = lsum; so0 = o0; so1 = o1;
      m = -1e30f; lsum = 0.f;
      #pragma unroll
      for (int r = 0; r < 16; ++r){ o0[r] = 0.f; o1[r] = 0.f; }
      q0s = gB*64 + wr*32;
      const u16* qp = qkv + base + (size_t)(q0s + (l & 31)) * QKVC + (l >> 5) * 8;
      #pragma unroll
      for (int dd = 0; dd < 4; ++dd) qf[dd] = *(const bf16x8*)(qp + dd*16);
      asm volatile("s_waitcnt vmcnt(0)" ::: "memory");  // q ready (one-time drain)
      __builtin_amdgcn_sched_barrier(0);
    }

    const bool act = gp ? true : (t < 16);   // A-waves idle on the last trip
    if (act){
      const int u = unit_of(t);

      // ---- QK^T: S^T[k 0..31][q], 4 MFMA
      f32x16 a0{};
      const int r0 = l & 31;
      #pragma unroll
      for (int dd = 0; dd < 4; ++dd){
        const int c = dd*2 + (l >> 5);
        const bf16x8 k0 = *(const bf16x8*)&Kreg[cb3*2048 + r0*64 + ((c ^ (r0 & 7)))*8];
        a0 = MFMA32(k0, qf[dd], a0);
      }

      // ---- causal mask (units reaching past the state's first q-row)
      if (u*32 + 31 > q0s){
        const int qg = q0s + (l & 31);
        #pragma unroll
        for (int r = 0; r < 16; ++r){
          const int kg = u*32 + (r & 3) + 8*(r >> 2) + 4*(l >> 5);
          if (kg > qg) a0[r] = -1e30f;
        }
      }

      // ---- row-max (shfl BEFORE tr issue — R14-verified ordering)
      float pm = -1e30f;
      #pragma unroll
      for (int r = 0; r < 16; ++r) pm = fmaxf(pm, a0[r]);
      pm = fmaxf(pm, __shfl(pm, l ^ 32));

      // ---- issue all 8 tr_reads; softmax below hides LDS latency
      s16x4 tr[8];
      {
        const u32 vb = vbytes + (u32)vb2 * 4096u;
        #pragma unroll
        for (int kk = 0; kk < 2; ++kk){
          asm volatile("ds_read_b64_tr_b16 %0, %4 offset:0\n\t"
                       "ds_read_b64_tr_b16 %1, %4 offset:512\n\t"
                       "ds_read_b64_tr_b16 %2, %4 offset:256\n\t"
                       "ds_read_b64_tr_b16 %3, %4 offset:768"
                       : "=&v"(tr[kk*4+0]), "=&v"(tr[kk*4+1]),
                         "=&v"(tr[kk*4+2]), "=&v"(tr[kk*4+3])
                       : "v"(vb + kk*2048));
        }
      }

      if (__any(pm > m + 64.f)){            // T13 defer-max
        const float mn = fmaxf(m, pm);
        const float corr = exp2f((m - mn) * CEXP);
        m = mn;
        lsum *= corr;
        #pragma unroll
        for (int r = 0; r < 16; ++r){
          const int row = (r & 3) + 8*(r >> 2) + 4*(l >> 5);
          const float cr = __shfl(corr, row | (l & 32));
          o0[r] *= cr; o1[r] *= cr;
        }
      }
      {
        float ls0 = 0.f, ls1 = 0.f;
        #pragma unroll
        for (int r = 0; r < 16; r += 2){
          const float p0 = exp2f((a0[r]   - m) * CEXP);
          const float p1 = exp2f((a0[r+1] - m) * CEXP);
          ls0 += p0; ls1 += p1;
          a0[r] = p0; a0[r+1] = p1;
        }
        lsum += ls0 + ls1;
      }

      // ---- wait V once, then PV: A-frag via cvt_pk + permlane32_swap
      asm volatile("s_waitcnt lgkmcnt(0)" ::: "memory");
      __builtin_amdgcn_sched_barrier(0);
      #pragma unroll
      for (int kk = 0; kk < 2; ++kk){
        const int o = kk * 8;
        const u32 x0 = pk2(a0[o+0], a0[o+1]);
        const u32 x1 = pk2(a0[o+2], a0[o+3]);
        const u32 y0 = pk2(a0[o+4], a0[o+5]);
        const u32 y1 = pk2(a0[o+6], a0[o+7]);
        const u32x2 r0v = __builtin_amdgcn_permlane32_swap(x0, y0, false, false);
        const u32x2 r1v = __builtin_amdgcn_permlane32_swap(x1, y1, false, false);
        union { u32 wd[4]; bf16x8 v; } af;
        af.wd[0] = r0v[0]; af.wd[1] = r1v[0]; af.wd[2] = r0v[1]; af.wd[3] = r1v[1];
        union { s16x4 hh[2]; bf16x8 v; } b0v, b1v;
        b0v.hh[0] = tr[kk*4+0]; b0v.hh[1] = tr[kk*4+1];
        b1v.hh[0] = tr[kk*4+2]; b1v.hh[1] = tr[kk*4+3];
        o0 = MFMA32(af.v, b0v.v, o0);
        o1 = MFMA32(af.v, b1v.v, o1);
      }
    }

    cb3 = (cb3 == 2) ? 0 : cb3 + 1;
    vb2 ^= 1;
  }

  // ---- finalize live state's half-sum; staging LDS dies after full drain
  lsum += __shfl(lsum, l ^ 32);
  __syncthreads();   // drains all DMA (incl. clamped restages) before LDS reuse

  // merge scratch in dead staging LDS: 6 wave-slots x 8KB + (m,l) slots
  float*  const MOf  = (float*)smem;                        // 48 KB
  float2* const MLml = (float2*)((char*)smem + 49152);      // 3 KB

  auto publish = [&](int s, float mm, float ll, const f32x16& p0, const f32x16& p1){
    const int ws = s*2 + wr;
    #pragma unroll
    for (int r = 0; r < 16; ++r){
      MOf[ws*2048 + l*32 + r]      = p0[r];
      MOf[ws*2048 + l*32 + 16 + r] = p1[r];
    }
    MLml[s*128 + wr*64 + l] = float2{mm, ll};
  };
  auto mergeWith = [&](int s, float& mm, float& ll, f32x16& p0, f32x16& p1){
    const int ws = s*2 + wr;
    const float2 o2 = MLml[s*128 + wr*64 + l];
    const float mx = fmaxf(mm, o2.x);
    const float c1 = exp2f((mm   - mx) * CEXP);
    const float c2 = exp2f((o2.x - mx) * CEXP);
    #pragma unroll
    for (int r = 0; r < 16; ++r){
      const int row = (r & 3) + 8*(r >> 2) + 4*(l >> 5);
      const float cr1 = __shfl(c1, row | (l & 32));
      const float cr2 = __shfl(c2, row | (l & 32));
      p0[r] = p0[r]*cr1 + MOf[ws*2048 + l*32 + r]*cr2;
      p1[r] = p1[r]*cr1 + MOf[ws*2048 + l*32 + 16 + r]*cr2;
    }
    mm = mx;
    ll = ll*c1 + o2.y*c2;
  };
  auto writeOut = [&](int g, float ll, const f32x16& p0, const f32x16& p1){
    const float inv = 1.0f / ll;
    #pragma unroll
    for (int r = 0; r < 16; ++r){
      const int row = (r & 3) + 8*(r >> 2) + 4*(l >> 5);
      const float ivr = __shfl(inv, row | (l & 32));
      const int qg = g*64 + wr*32 + row;
      u16* op = aout + (size_t)(b*SEQ + qg) * HIDDEN + h*64 + (l & 31);
      op[0]  = f2bf(p0[r] * ivr);
      op[32] = f2bf(p1[r] * ivr);
    }
  };

  // phase 1: hr1 waves publish; (A-hr1 publishes both its stashed-A and live B-help)
  if (gp == 1 && hr == 1) publish(0, m, lsum, o0, o1);          // B-main-hr1
  if (gp == 0 && hr == 1){
    publish(1, m, lsum, o0, o1);                                 // B-help-hr1 (live)
    publish(2, sm, sl, so0, so1);                                // A-hr1 (stashed)
  }
  __syncthreads();

  if (gp == 1 && hr == 0) mergeWith(0, m, lsum, o0, o1);         // B-main combined
  if (gp == 0 && hr == 0){
    mergeWith(2, sm, sl, so0, so1);                              // A combined
    writeOut(gA, sl, so0, so1);                                  // A FINAL
    mergeWith(1, m, lsum, o0, o1);                               // B-help combined
  }
  __syncthreads();

  // phase 2: hr0 A-wave republishes combined B-help; B hr0 wave merges + writes
  if (gp == 0 && hr == 0) publish(0, m, lsum, o0, o1);
  __syncthreads();
  if (gp == 1 && hr == 0){
    mergeWith(0, m, lsum, o0, o1);                               // B FINAL
    writeOut(gB, lsum, o0, o1);
  }
}

// ---------------- launch ----------------
extern "C" void kernel_launch(void* const* d_in, const int* in_sizes, int n_in,
                              void* d_out, int out_size, void* d_ws, size_t ws_size,
                              hipStream_t stream){
  const float* enc    = (const float*)d_in[0];
  const float* attn_w = (const float*)d_in[1];
  const float* attn_b = (const float*)d_in[2];
  const float* out_w  = (const float*)d_in[3];
  const float* out_b  = (const float*)d_in[4];

  char* ws = (char*)d_ws;
  u16* enc_bf = (u16*)(ws);
  u16* wa_bf  = (u16*)(ws + (size_t)( 8u << 20));
  u16* wo_bf  = (u16*)(ws + (size_t)(14u << 20));
  u16* qkv    = (u16*)(ws + (size_t)(16u << 20));
  u16* aout   = enc_bf;  // safe alias: attn runs strictly after GEMM1

  k_cvt3<<<dim3((CVT_N0+CVT_N1+CVT_N2 + 255)/256), 256, 0, stream>>>(
      enc, attn_w, out_w, enc_bf, wa_bf, wo_bf);

  k_gemm<QKVC,  true ><<<dim3(MROWS/128, QKVC/128),  256, 0, stream>>>(enc_bf, wa_bf, attn_b, qkv);
  k_attn<<<dim3(32, 16), 512, 0, stream>>>(qkv, aout);
  k_gemm<HIDDEN, false><<<dim3(MROWS/128, HIDDEN/128), 256, 0, stream>>>(aout, wo_bf, out_b, d_out);
}

// Round 19
// 105.555 us; speedup vs baseline: 1.2396x; 1.2396x over previous
//
#include <hip/hip_runtime.h>
#include <hip/hip_bf16.h>
#include <stdint.h>

#define HIDDEN 1024
#define NHEADS 16
#define DHEAD  64
#define BATCH  2
#define SEQ    2048
#define MROWS  (BATCH*SEQ)   // 4096
#define QKVC   (3*HIDDEN)    // 3072

typedef unsigned short u16;
typedef unsigned int   u32;
typedef __bf16 bf16x8 __attribute__((ext_vector_type(8)));
typedef __bf16 bf16x2 __attribute__((ext_vector_type(2)));
typedef float  f32x4  __attribute__((ext_vector_type(4)));
typedef float  f32x16 __attribute__((ext_vector_type(16)));
typedef short  s16x4  __attribute__((ext_vector_type(4)));
typedef u16    u16x8  __attribute__((ext_vector_type(8)));
typedef u32    u32x2  __attribute__((ext_vector_type(2)));

typedef const __attribute__((address_space(1))) void gvoid_t;
typedef       __attribute__((address_space(3))) void lvoid_t;

__device__ __forceinline__ gvoid_t* to_glob(const void* p){
  return (gvoid_t*)(uintptr_t)p;
}
__device__ __forceinline__ lvoid_t* to_lds(void* p){
  return (lvoid_t*)(uintptr_t)p;
}
__device__ __forceinline__ u32 lds_off(const void* p){
  return (u32)(uintptr_t)p;
}

// native f32->bf16 (hardware RNE cvt on gfx950)
__device__ __forceinline__ u16 f2bf(float x){
  __bf16 h = (__bf16)x;
  return __builtin_bit_cast(u16, h);
}
// packed f32x2 -> bf16x2 word (compiler emits v_cvt_pk_bf16_f32)
__device__ __forceinline__ u32 pk2(float a, float b){
  bf16x2 t = { (__bf16)a, (__bf16)b };
  return __builtin_bit_cast(u32, t);
}

#define MFMA32(a, b, c) __builtin_amdgcn_mfma_f32_32x32x16_bf16(a, b, c, 0, 0, 0)

// ---------------- fp32 -> bf16 conversion, all 3 inputs in one launch ----------------
#define CVT_N0 1048576   // enc      (4M f32 / 4)
#define CVT_N1  786432   // attn_w   (3M f32 / 4)
#define CVT_N2  262144   // out_w    (1M f32 / 4)
__global__ __launch_bounds__(256) void k_cvt3(const float* __restrict__ e,
                                              const float* __restrict__ wa,
                                              const float* __restrict__ wo,
                                              u16* __restrict__ eb,
                                              u16* __restrict__ wab,
                                              u16* __restrict__ wob){
  int i = blockIdx.x * 256 + threadIdx.x;
  const float* src; u16* dst;
  if (i < CVT_N0){ src = e; dst = eb; }
  else if (i < CVT_N0 + CVT_N1){ i -= CVT_N0; src = wa; dst = wab; }
  else if (i < CVT_N0 + CVT_N1 + CVT_N2){ i -= CVT_N0 + CVT_N1; src = wo; dst = wob; }
  else return;
  const float4 v = reinterpret_cast<const float4*>(src)[i];
  ushort4 o;
  o.x = f2bf(v.x); o.y = f2bf(v.y); o.z = f2bf(v.z); o.w = f2bf(v.w);
  reinterpret_cast<ushort4*>(dst)[i] = o;
}

// ---------------- bf16 GEMM, C = A * B^T + bias (R12-verified, no swizzle) ----------------
// 128x128 tile, BK=32, 2-phase prefetch (stage(t+1) before compute(t), one
// __syncthreads per K-step). T1 XCD swizzle removed: weights are L3-fit, and
// m160/R14 showed it neutral-to-negative in that regime.
template<int NC, bool BF16OUT>
__global__ __launch_bounds__(256) void k_gemm(const u16* __restrict__ A,
                                              const u16* __restrict__ B,
                                              const float* __restrict__ bias,
                                              void* __restrict__ C){
  constexpr int K = HIDDEN;
  __shared__ u16 As[2][128*32];
  __shared__ u16 Bs[2][128*32];
  const int m0 = blockIdx.x * 128;
  const int n0 = blockIdx.y * 128;
  const int tid = threadIdx.x;
  const int w = tid >> 6, l = tid & 63;
  const int wr = w >> 1, wc = w & 1;

  const f32x4 fz = {0.f, 0.f, 0.f, 0.f};
  f32x4 acc[4][4];
  #pragma unroll
  for (int i = 0; i < 4; ++i)
    #pragma unroll
    for (int j = 0; j < 4; ++j) acc[i][j] = fz;

  const u16* ap = A + (size_t)(m0 + (tid >> 2)) * K + (tid & 3) * 8;
  const u16* bp = B + (size_t)(n0 + (tid >> 2)) * K + (tid & 3) * 8;

  auto stage = [&](int k0, int buf){
    __builtin_amdgcn_global_load_lds(to_glob(ap + k0),        to_lds(&As[buf][w*512]),        16, 0, 0);
    __builtin_amdgcn_global_load_lds(to_glob(ap + 64*K + k0), to_lds(&As[buf][2048 + w*512]), 16, 0, 0);
    __builtin_amdgcn_global_load_lds(to_glob(bp + k0),        to_lds(&Bs[buf][w*512]),        16, 0, 0);
    __builtin_amdgcn_global_load_lds(to_glob(bp + 64*K + k0), to_lds(&Bs[buf][2048 + w*512]), 16, 0, 0);
  };

  stage(0, 0);
  __syncthreads();

  for (int k0 = 0; k0 < K; k0 += 32){
    const int cur = (k0 >> 5) & 1;
    if (k0 + 32 < K) stage(k0 + 32, cur ^ 1);

    bf16x8 af[4], bfr[4];
    #pragma unroll
    for (int mf = 0; mf < 4; ++mf)
      af[mf]  = *(const bf16x8*)&As[cur][(wr*64 + mf*16 + (l & 15))*32 + (l >> 4)*8];
    #pragma unroll
    for (int nf = 0; nf < 4; ++nf)
      bfr[nf] = *(const bf16x8*)&Bs[cur][(wc*64 + nf*16 + (l & 15))*32 + (l >> 4)*8];
    #pragma unroll
    for (int mf = 0; mf < 4; ++mf)
      #pragma unroll
      for (int nf = 0; nf < 4; ++nf)
        acc[mf][nf] = __builtin_amdgcn_mfma_f32_16x16x32_bf16(af[mf], bfr[nf], acc[mf][nf], 0, 0, 0);

    __syncthreads();
  }

  #pragma unroll
  for (int nf = 0; nf < 4; ++nf){
    const int col = n0 + wc*64 + nf*16 + (l & 15);
    const float bv = bias[col];
    #pragma unroll
    for (int mf = 0; mf < 4; ++mf){
      #pragma unroll
      for (int r = 0; r < 4; ++r){
        const int row = m0 + wr*64 + mf*16 + (l >> 4)*4 + r;
        const float v = acc[mf][nf][r] + bv;
        if constexpr (BF16OUT) ((u16*)C)[(size_t)row * NC + col] = f2bf(v);
        else                   ((float*)C)[(size_t)row * NC + col] = v;
      }
    }
  }
}

// ---------------- causal flash attention: counted-vmcnt, K 3-buf / V 2-buf ----
// EXACT R12 (verified 45.8us / absmax 0.0049; best total 105.6us).
// grid = (32 bh, 32 qt LPT), block 256 = 4 waves (hr = k-half, wr = q-half).
// Own-vmcnt(2) wait BEFORE raw s_barrier (no drain); K triple-buffered
// (distance-2), V double-buffered (distance-1). Ledger: prologue K0,V0,K1;
// per iter wait vmcnt(2) [K(it),V(it) landed, K(it+1) in flight], then issue
// V(it+1) BEFORE K(it+2). Tail prefetches clamp to kmax. 40 KiB -> 4 blk/CU.
// Post-mortem consolidation notes (R13-R18): 4 blocks/CU is this structure's
// LDS max; causal-tail equalization (R18) spills (needs >128 VGPR state at
// <=128 VGPR residency) — structural dead end. permlane32_swap(x,x)
// self-swap is BANNED (R15/R16 failures).
__global__ __launch_bounds__(256, 4) void k_attn(const u16* __restrict__ qkv,
                                                 u16* __restrict__ aout){
  __shared__ u16 smem[20480];   // 40 KiB: half hr at [hr*10240]: K 3x2048 | V 2x2048 (u16)

  const int bh = blockIdx.x;
  const int b  = bh >> 4;
  const int h  = bh & 15;
  const int qt = 31 - blockIdx.y;          // LPT: longest blocks first
  const int tid = threadIdx.x;
  const int l  = tid & 63;
  const int w  = tid >> 6;
  const int hr = w >> 1;                   // k-half (0 or 1)
  const int wr = w & 1;                    // q-row half within tile
  const int t128 = tid & 127;
  const int lw = t128 >> 6;                // wave-within-half
  const int U  = qt + 1;                   // 32-k units per half (uniform)
  const int kb = hr ? U : 0;               // my first unit
  const int kmax = kb + U - 1;             // clamp target for tail prefetch
  const int q0 = qt*64 + wr*32;            // this wave's 32 q-rows
  const size_t base = (size_t)b * SEQ * QKVC + (size_t)h * 192;
  const float CEXP = 0.18033688011112042f; // 0.125 * log2(e)

  u16* const Kreg = smem + hr*10240;          // + cb*2048 (u16), cb in {0,1,2}
  u16* const Vreg = smem + hr*10240 + 6144;   // + vb*2048 (u16), vb in {0,1}

  // ---- per-lane staging source bases (XOR pre-swizzled K; inverse-subtile V)
  const int cgK = (t128 & 7) ^ ((t128 >> 3) & 7);
  const u16* const baseK = qkv + base + (size_t)(t128 >> 3) * QKVC + 64 + cgK * 8;
  const int vk = ((t128 >> 5) << 2) | ((t128 >> 1) & 3);
  const int vd = (((t128 >> 3) & 3) << 4) | ((t128 & 1) << 3);
  const u16* const baseV = qkv + base + (size_t)vk * QKVC + 128 + vd;

  auto stageK = [&](int u, int cb){   // 2 vmem instrs per wave
    const u16* pk = baseK + (size_t)u * 32 * QKVC;
    #pragma unroll
    for (int t = 0; t < 2; ++t)
      __builtin_amdgcn_global_load_lds(to_glob(pk + t*16*QKVC),
                                       to_lds(&Kreg[cb*2048 + t*1024 + lw*512]), 16, 0, 0);
  };
  auto stageV = [&](int u, int vb){   // 2 vmem instrs per wave
    const u16* pv = baseV + (size_t)u * 32 * QKVC;
    #pragma unroll
    for (int t = 0; t < 2; ++t)
      __builtin_amdgcn_global_load_lds(to_glob(pv + t*16*QKVC),
                                       to_lds(&Vreg[vb*2048 + t*1024 + lw*512]), 16, 0, 0);
  };

  // Q B-frags: col=q=(l&31), k-dim=d=(l>>5)*8 + dd*16 + j
  bf16x8 qf[4];
  {
    const u16* qp = qkv + base + (size_t)(q0 + (l & 31)) * QKVC + (l >> 5) * 8;
    #pragma unroll
    for (int dd = 0; dd < 4; ++dd) qf[dd] = *(const bf16x8*)(qp + dd*16);
  }

  f32x16 o0{}, o1{};              // O[q=row(r)][d=(l&31)+{0,32}]
  float m = -1e30f, lsum = 0.f;   // per-lane (q = l&31, own k-rows)

  // prologue ledger: K0, V0, K1 (6 ops outstanding; qf loads ahead of them)
  stageK(kb, 0);
  stageV(kb, 0);
  stageK(kb + (U > 1 ? 1 : 0), 1);

  const u32 vbytes = lds_off(Vreg) + (l & 15)*8 + ((l >> 4) & 1)*128 + (l >> 5)*1024;

  int cb3 = 0;                    // it % 3 (K buffer)
  int vb2 = 0;                    // it % 2 (V buffer)
  for (int it = 0; it < U; ++it){
    const int u = kb + it;

    // own K(it)+V(it) landed (K(it+1) stays in flight); then align waves, NO drain
    asm volatile("s_waitcnt vmcnt(2)" ::: "memory");
    __builtin_amdgcn_sched_barrier(0);
    __builtin_amdgcn_s_barrier();
    __builtin_amdgcn_sched_barrier(0);

    // V before K (keeps the two unwaited ops == next-K); clamp at tail
    stageV(u + 1 > kmax ? kmax : u + 1, vb2 ^ 1);
    stageK(u + 2 > kmax ? kmax : u + 2, cb3 == 0 ? 2 : cb3 - 1);

    // ---- QK^T: S^T[k 0..31][q], 4 MFMA
    f32x16 a0{};
    const int r0 = l & 31;
    #pragma unroll
    for (int dd = 0; dd < 4; ++dd){
      const int c = dd*2 + (l >> 5);
      const bf16x8 k0 = *(const bf16x8*)&Kreg[cb3*2048 + r0*64 + ((c ^ (r0 & 7)))*8];
      a0 = MFMA32(k0, qf[dd], a0);
    }

    // ---- causal mask (units reaching past the wave's first q-row)
    if (u*32 + 31 > q0){
      const int qg = q0 + (l & 31);
      #pragma unroll
      for (int r = 0; r < 16; ++r){
        const int kg = u*32 + (r & 3) + 8*(r >> 2) + 4*(l >> 5);
        if (kg > qg) a0[r] = -1e30f;
      }
    }

    // ---- row-max
    float pm = -1e30f;
    #pragma unroll
    for (int r = 0; r < 16; ++r) pm = fmaxf(pm, a0[r]);
    pm = fmaxf(pm, __shfl(pm, l ^ 32));

    // ---- issue all 8 tr_reads; softmax below hides LDS latency
    s16x4 tr[8];
    {
      const u32 vb = vbytes + (u32)vb2 * 4096u;
      #pragma unroll
      for (int kk = 0; kk < 2; ++kk){
        asm volatile("ds_read_b64_tr_b16 %0, %4 offset:0\n\t"
                     "ds_read_b64_tr_b16 %1, %4 offset:512\n\t"
                     "ds_read_b64_tr_b16 %2, %4 offset:256\n\t"
                     "ds_read_b64_tr_b16 %3, %4 offset:768"
                     : "=&v"(tr[kk*4+0]), "=&v"(tr[kk*4+1]),
                       "=&v"(tr[kk*4+2]), "=&v"(tr[kk*4+3])
                     : "v"(vb + kk*2048));
      }
    }

    if (__any(pm > m + 64.f)){            // T13 defer-max
      const float mn = fmaxf(m, pm);
      const float corr = exp2f((m - mn) * CEXP);
      m = mn;
      lsum *= corr;
      #pragma unroll
      for (int r = 0; r < 16; ++r){
        const int row = (r & 3) + 8*(r >> 2) + 4*(l >> 5);
        const float cr = __shfl(corr, row | (l & 32));
        o0[r] *= cr; o1[r] *= cr;
      }
    }
    #pragma unroll
    for (int r = 0; r < 16; ++r){
      const float p = exp2f((a0[r] - m) * CEXP);
      lsum += p;
      a0[r] = p;
    }

    // ---- wait V once, then PV: A-frag via cvt_pk + permlane32_swap
    asm volatile("s_waitcnt lgkmcnt(0)" ::: "memory");
    __builtin_amdgcn_sched_barrier(0);
    #pragma unroll
    for (int kk = 0; kk < 2; ++kk){
      const int o = kk * 8;
      const u32 x0 = pk2(a0[o+0], a0[o+1]);
      const u32 x1 = pk2(a0[o+2], a0[o+3]);
      const u32 y0 = pk2(a0[o+4], a0[o+5]);
      const u32 y1 = pk2(a0[o+6], a0[o+7]);
      const u32x2 r0v = __builtin_amdgcn_permlane32_swap(x0, y0, false, false);
      const u32x2 r1v = __builtin_amdgcn_permlane32_swap(x1, y1, false, false);
      union { u32 wd[4]; bf16x8 v; } af;
      af.wd[0] = r0v[0]; af.wd[1] = r1v[0]; af.wd[2] = r0v[1]; af.wd[3] = r1v[1];
      union { s16x4 hh[2]; bf16x8 v; } b0, b1;
      b0.hh[0] = tr[kk*4+0]; b0.hh[1] = tr[kk*4+1];
      b1.hh[0] = tr[kk*4+2]; b1.hh[1] = tr[kk*4+3];
      o0 = MFMA32(af.v, b0.v, o0);
      o1 = MFMA32(af.v, b1.v, o1);
    }

    cb3 = (cb3 == 2) ? 0 : cb3 + 1;
    vb2 ^= 1;
  }

  // ---- cross-half merge (once): __syncthreads drains all DMA before LDS reuse
  lsum += __shfl(lsum, l ^ 32);             // combine lane k-halves (same q)
  __syncthreads();
  float* const Osh  = (float*)smem;                         // 16 KB
  float2* const MLsh = (float2*)((char*)smem + 16384);      // 1 KB

  if (hr == 1){
    #pragma unroll
    for (int r = 0; r < 16; ++r){
      Osh[wr*2048 + l*32 + r]      = o0[r];
      Osh[wr*2048 + l*32 + 16 + r] = o1[r];
    }
    MLsh[wr*64 + l] = float2{m, lsum};
  }
  __syncthreads();

  if (hr == 0){
    const float2 ml1 = MLsh[wr*64 + l];
    const float mm = fmaxf(m, ml1.x);
    const float c0 = exp2f((m - mm) * CEXP);
    const float c1 = exp2f((ml1.x - mm) * CEXP);
    const float lm = lsum*c0 + ml1.y*c1;    // >0 always (half-0 non-empty)
    const float a0q = c0 / lm;
    const float a1q = c1 / lm;
    #pragma unroll
    for (int r = 0; r < 16; ++r){
      const int row = (r & 3) + 8*(r >> 2) + 4*(l >> 5);
      const float f0 = __shfl(a0q, row | (l & 32));
      const float f1 = __shfl(a1q, row | (l & 32));
      const int qg = q0 + row;
      u16* op = aout + (size_t)(b*SEQ + qg) * HIDDEN + h*64 + (l & 31);
      op[0]  = f2bf(o0[r]*f0 + Osh[wr*2048 + l*32 + r]*f1);
      op[32] = f2bf(o1[r]*f0 + Osh[wr*2048 + l*32 + 16 + r]*f1);
    }
  }
}

// ---------------- launch ----------------
extern "C" void kernel_launch(void* const* d_in, const int* in_sizes, int n_in,
                              void* d_out, int out_size, void* d_ws, size_t ws_size,
                              hipStream_t stream){
  const float* enc    = (const float*)d_in[0];
  const float* attn_w = (const float*)d_in[1];
  const float* attn_b = (const float*)d_in[2];
  const float* out_w  = (const float*)d_in[3];
  const float* out_b  = (const float*)d_in[4];

  char* ws = (char*)d_ws;
  u16* enc_bf = (u16*)(ws);
  u16* wa_bf  = (u16*)(ws + (size_t)( 8u << 20));
  u16* wo_bf  = (u16*)(ws + (size_t)(14u << 20));
  u16* qkv    = (u16*)(ws + (size_t)(16u << 20));
  u16* aout   = enc_bf;  // safe alias: attn runs strictly after GEMM1

  k_cvt3<<<dim3((CVT_N0+CVT_N1+CVT_N2 + 255)/256), 256, 0, stream>>>(
      enc, attn_w, out_w, enc_bf, wa_bf, wo_bf);

  k_gemm<QKVC,  true ><<<dim3(MROWS/128, QKVC/128),  256, 0, stream>>>(enc_bf, wa_bf, attn_b, qkv);
  k_attn<<<dim3(32, 32), 256, 0, stream>>>(qkv, aout);
  k_gemm<HIDDEN, false><<<dim3(MROWS/128, HIDDEN/128), 256, 0, stream>>>(aout, wo_bf, out_b, d_out);
}

// Round 20
// 104.733 us; speedup vs baseline: 1.2493x; 1.0079x over previous
//
#include <hip/hip_runtime.h>
#include <hip/hip_bf16.h>
#include <stdint.h>

#define HIDDEN 1024
#define NHEADS 16
#define DHEAD  64
#define BATCH  2
#define SEQ    2048
#define MROWS  (BATCH*SEQ)   // 4096
#define QKVC   (3*HIDDEN)    // 3072

typedef unsigned short u16;
typedef unsigned int   u32;
typedef __bf16 bf16x8 __attribute__((ext_vector_type(8)));
typedef __bf16 bf16x2 __attribute__((ext_vector_type(2)));
typedef float  f32x4  __attribute__((ext_vector_type(4)));
typedef float  f32x16 __attribute__((ext_vector_type(16)));
typedef short  s16x4  __attribute__((ext_vector_type(4)));
typedef u16    u16x8  __attribute__((ext_vector_type(8)));
typedef u32    u32x2  __attribute__((ext_vector_type(2)));

typedef const __attribute__((address_space(1))) void gvoid_t;
typedef       __attribute__((address_space(3))) void lvoid_t;

__device__ __forceinline__ gvoid_t* to_glob(const void* p){
  return (gvoid_t*)(uintptr_t)p;
}
__device__ __forceinline__ lvoid_t* to_lds(void* p){
  return (lvoid_t*)(uintptr_t)p;
}
__device__ __forceinline__ u32 lds_off(const void* p){
  return (u32)(uintptr_t)p;
}

// native f32->bf16 (hardware RNE cvt on gfx950)
__device__ __forceinline__ u16 f2bf(float x){
  __bf16 h = (__bf16)x;
  return __builtin_bit_cast(u16, h);
}
// packed f32x2 -> bf16x2 word (compiler emits v_cvt_pk_bf16_f32)
__device__ __forceinline__ u32 pk2(float a, float b){
  bf16x2 t = { (__bf16)a, (__bf16)b };
  return __builtin_bit_cast(u32, t);
}

#define MFMA32(a, b, c) __builtin_amdgcn_mfma_f32_32x32x16_bf16(a, b, c, 0, 0, 0)

// ---------------- fp32 -> bf16 conversion, all 3 inputs in one launch ----------------
#define CVT_N0 1048576   // enc      (4M f32 / 4)
#define CVT_N1  786432   // attn_w   (3M f32 / 4)
#define CVT_N2  262144   // out_w    (1M f32 / 4)
__global__ __launch_bounds__(256) void k_cvt3(const float* __restrict__ e,
                                              const float* __restrict__ wa,
                                              const float* __restrict__ wo,
                                              u16* __restrict__ eb,
                                              u16* __restrict__ wab,
                                              u16* __restrict__ wob){
  int i = blockIdx.x * 256 + threadIdx.x;
  const float* src; u16* dst;
  if (i < CVT_N0){ src = e; dst = eb; }
  else if (i < CVT_N0 + CVT_N1){ i -= CVT_N0; src = wa; dst = wab; }
  else if (i < CVT_N0 + CVT_N1 + CVT_N2){ i -= CVT_N0 + CVT_N1; src = wo; dst = wob; }
  else return;
  const float4 v = reinterpret_cast<const float4*>(src)[i];
  ushort4 o;
  o.x = f2bf(v.x); o.y = f2bf(v.y); o.z = f2bf(v.z); o.w = f2bf(v.w);
  reinterpret_cast<ushort4*>(dst)[i] = o;
}

// ---------------- bf16 GEMM, C = A * B^T + bias ----------------
// R20: T2 LDS XOR-swizzle. Diagnosis: 64B rows => fragment read (16 rows,
// fixed chunk) = 8-way bank conflict (2.94x LDS cost, m136) => ~580 TF LDS
// ceiling, right where the gemm sat. Fix per rule #21 (mirrors the attn-K
// staging verified since R5): LDS dest stays LINEAR for global_load_lds, the
// GLOBAL source chunk is pre-swizzled, reads apply the same involution.
//   write: lane tid stages row tid>>2, src chunk sc=(tid&3)^(((tid>>2)>>1)&3)
//   read : row r, wanted chunk g=(l>>4) -> LDS chunk g^((r>>1)&3) = g^((l>>1)&3)
// Result: 64 lanes read 64 DISTINCT 16B chunks -> aggregate conflict-free.
template<int NC, bool BF16OUT>
__global__ __launch_bounds__(256) void k_gemm(const u16* __restrict__ A,
                                              const u16* __restrict__ B,
                                              const float* __restrict__ bias,
                                              void* __restrict__ C){
  constexpr int K = HIDDEN;
  __shared__ u16 As[2][128*32];
  __shared__ u16 Bs[2][128*32];
  const int m0 = blockIdx.x * 128;
  const int n0 = blockIdx.y * 128;
  const int tid = threadIdx.x;
  const int w = tid >> 6, l = tid & 63;
  const int wr = w >> 1, wc = w & 1;

  const f32x4 fz = {0.f, 0.f, 0.f, 0.f};
  f32x4 acc[4][4];
  #pragma unroll
  for (int i = 0; i < 4; ++i)
    #pragma unroll
    for (int j = 0; j < 4; ++j) acc[i][j] = fz;

  // pre-swizzled source chunk (involution; same (row>>1)&3 term for both
  // 64-row halves since (64+x)>>1 adds 32 -> &3 unchanged)
  const int sc = (tid & 3) ^ (((tid >> 2) >> 1) & 3);
  const u16* ap = A + (size_t)(m0 + (tid >> 2)) * K + sc * 8;
  const u16* bp = B + (size_t)(n0 + (tid >> 2)) * K + sc * 8;

  auto stage = [&](int k0, int buf){
    __builtin_amdgcn_global_load_lds(to_glob(ap + k0),        to_lds(&As[buf][w*512]),        16, 0, 0);
    __builtin_amdgcn_global_load_lds(to_glob(ap + 64*K + k0), to_lds(&As[buf][2048 + w*512]), 16, 0, 0);
    __builtin_amdgcn_global_load_lds(to_glob(bp + k0),        to_lds(&Bs[buf][w*512]),        16, 0, 0);
    __builtin_amdgcn_global_load_lds(to_glob(bp + 64*K + k0), to_lds(&Bs[buf][2048 + w*512]), 16, 0, 0);
  };

  stage(0, 0);
  __syncthreads();

  const int chunkSel = ((l >> 4) ^ ((l >> 1) & 3)) * 8;   // swizzled read chunk

  for (int k0 = 0; k0 < K; k0 += 32){
    const int cur = (k0 >> 5) & 1;
    if (k0 + 32 < K) stage(k0 + 32, cur ^ 1);

    bf16x8 af[4], bfr[4];
    #pragma unroll
    for (int mf = 0; mf < 4; ++mf)
      af[mf]  = *(const bf16x8*)&As[cur][(wr*64 + mf*16 + (l & 15))*32 + chunkSel];
    #pragma unroll
    for (int nf = 0; nf < 4; ++nf)
      bfr[nf] = *(const bf16x8*)&Bs[cur][(wc*64 + nf*16 + (l & 15))*32 + chunkSel];
    #pragma unroll
    for (int mf = 0; mf < 4; ++mf)
      #pragma unroll
      for (int nf = 0; nf < 4; ++nf)
        acc[mf][nf] = __builtin_amdgcn_mfma_f32_16x16x32_bf16(af[mf], bfr[nf], acc[mf][nf], 0, 0, 0);

    __syncthreads();
  }

  #pragma unroll
  for (int nf = 0; nf < 4; ++nf){
    const int col = n0 + wc*64 + nf*16 + (l & 15);
    const float bv = bias[col];
    #pragma unroll
    for (int mf = 0; mf < 4; ++mf){
      #pragma unroll
      for (int r = 0; r < 4; ++r){
        const int row = m0 + wr*64 + mf*16 + (l >> 4)*4 + r;
        const float v = acc[mf][nf][r] + bv;
        if constexpr (BF16OUT) ((u16*)C)[(size_t)row * NC + col] = f2bf(v);
        else                   ((float*)C)[(size_t)row * NC + col] = v;
      }
    }
  }
}

// ---------------- causal flash attention: counted-vmcnt, K 3-buf / V 2-buf ----
// EXACT R12/R19 (verified 45.8-46.5us / absmax 0.0049).
// grid = (32 bh, 32 qt LPT), block 256 = 4 waves (hr = k-half, wr = q-half).
// Own-vmcnt(2) wait BEFORE raw s_barrier (no drain); K triple-buffered
// (distance-2), V double-buffered (distance-1). Ledger: prologue K0,V0,K1;
// per iter wait vmcnt(2) [K(it),V(it) landed, K(it+1) in flight], then issue
// V(it+1) BEFORE K(it+2). Tail prefetches clamp to kmax. 40 KiB -> 4 blk/CU.
// Known dead ends (R13-R18): sync-scheme changes are plateau-neutral; tail
// equalization spills; permlane32_swap(x,x) self-swap is BANNED.
__global__ __launch_bounds__(256, 4) void k_attn(const u16* __restrict__ qkv,
                                                 u16* __restrict__ aout){
  __shared__ u16 smem[20480];   // 40 KiB: half hr at [hr*10240]: K 3x2048 | V 2x2048 (u16)

  const int bh = blockIdx.x;
  const int b  = bh >> 4;
  const int h  = bh & 15;
  const int qt = 31 - blockIdx.y;          // LPT: longest blocks first
  const int tid = threadIdx.x;
  const int l  = tid & 63;
  const int w  = tid >> 6;
  const int hr = w >> 1;                   // k-half (0 or 1)
  const int wr = w & 1;                    // q-row half within tile
  const int t128 = tid & 127;
  const int lw = t128 >> 6;                // wave-within-half
  const int U  = qt + 1;                   // 32-k units per half (uniform)
  const int kb = hr ? U : 0;               // my first unit
  const int kmax = kb + U - 1;             // clamp target for tail prefetch
  const int q0 = qt*64 + wr*32;            // this wave's 32 q-rows
  const size_t base = (size_t)b * SEQ * QKVC + (size_t)h * 192;
  const float CEXP = 0.18033688011112042f; // 0.125 * log2(e)

  u16* const Kreg = smem + hr*10240;          // + cb*2048 (u16), cb in {0,1,2}
  u16* const Vreg = smem + hr*10240 + 6144;   // + vb*2048 (u16), vb in {0,1}

  // ---- per-lane staging source bases (XOR pre-swizzled K; inverse-subtile V)
  const int cgK = (t128 & 7) ^ ((t128 >> 3) & 7);
  const u16* const baseK = qkv + base + (size_t)(t128 >> 3) * QKVC + 64 + cgK * 8;
  const int vk = ((t128 >> 5) << 2) | ((t128 >> 1) & 3);
  const int vd = (((t128 >> 3) & 3) << 4) | ((t128 & 1) << 3);
  const u16* const baseV = qkv + base + (size_t)vk * QKVC + 128 + vd;

  auto stageK = [&](int u, int cb){   // 2 vmem instrs per wave
    const u16* pk = baseK + (size_t)u * 32 * QKVC;
    #pragma unroll
    for (int t = 0; t < 2; ++t)
      __builtin_amdgcn_global_load_lds(to_glob(pk + t*16*QKVC),
                                       to_lds(&Kreg[cb*2048 + t*1024 + lw*512]), 16, 0, 0);
  };
  auto stageV = [&](int u, int vb){   // 2 vmem instrs per wave
    const u16* pv = baseV + (size_t)u * 32 * QKVC;
    #pragma unroll
    for (int t = 0; t < 2; ++t)
      __builtin_amdgcn_global_load_lds(to_glob(pv + t*16*QKVC),
                                       to_lds(&Vreg[vb*2048 + t*1024 + lw*512]), 16, 0, 0);
  };

  // Q B-frags: col=q=(l&31), k-dim=d=(l>>5)*8 + dd*16 + j
  bf16x8 qf[4];
  {
    const u16* qp = qkv + base + (size_t)(q0 + (l & 31)) * QKVC + (l >> 5) * 8;
    #pragma unroll
    for (int dd = 0; dd < 4; ++dd) qf[dd] = *(const bf16x8*)(qp + dd*16);
  }

  f32x16 o0{}, o1{};              // O[q=row(r)][d=(l&31)+{0,32}]
  float m = -1e30f, lsum = 0.f;   // per-lane (q = l&31, own k-rows)

  // prologue ledger: K0, V0, K1 (6 ops outstanding; qf loads ahead of them)
  stageK(kb, 0);
  stageV(kb, 0);
  stageK(kb + (U > 1 ? 1 : 0), 1);

  const u32 vbytes = lds_off(Vreg) + (l & 15)*8 + ((l >> 4) & 1)*128 + (l >> 5)*1024;

  int cb3 = 0;                    // it % 3 (K buffer)
  int vb2 = 0;                    // it % 2 (V buffer)
  for (int it = 0; it < U; ++it){
    const int u = kb + it;

    // own K(it)+V(it) landed (K(it+1) stays in flight); then align waves, NO drain
    asm volatile("s_waitcnt vmcnt(2)" ::: "memory");
    __builtin_amdgcn_sched_barrier(0);
    __builtin_amdgcn_s_barrier();
    __builtin_amdgcn_sched_barrier(0);

    // V before K (keeps the two unwaited ops == next-K); clamp at tail
    stageV(u + 1 > kmax ? kmax : u + 1, vb2 ^ 1);
    stageK(u + 2 > kmax ? kmax : u + 2, cb3 == 0 ? 2 : cb3 - 1);

    // ---- QK^T: S^T[k 0..31][q], 4 MFMA
    f32x16 a0{};
    const int r0 = l & 31;
    #pragma unroll
    for (int dd = 0; dd < 4; ++dd){
      const int c = dd*2 + (l >> 5);
      const bf16x8 k0 = *(const bf16x8*)&Kreg[cb3*2048 + r0*64 + ((c ^ (r0 & 7)))*8];
      a0 = MFMA32(k0, qf[dd], a0);
    }

    // ---- causal mask (units reaching past the wave's first q-row)
    if (u*32 + 31 > q0){
      const int qg = q0 + (l & 31);
      #pragma unroll
      for (int r = 0; r < 16; ++r){
        const int kg = u*32 + (r & 3) + 8*(r >> 2) + 4*(l >> 5);
        if (kg > qg) a0[r] = -1e30f;
      }
    }

    // ---- row-max
    float pm = -1e30f;
    #pragma unroll
    for (int r = 0; r < 16; ++r) pm = fmaxf(pm, a0[r]);
    pm = fmaxf(pm, __shfl(pm, l ^ 32));

    // ---- issue all 8 tr_reads; softmax below hides LDS latency
    s16x4 tr[8];
    {
      const u32 vb = vbytes + (u32)vb2 * 4096u;
      #pragma unroll
      for (int kk = 0; kk < 2; ++kk){
        asm volatile("ds_read_b64_tr_b16 %0, %4 offset:0\n\t"
                     "ds_read_b64_tr_b16 %1, %4 offset:512\n\t"
                     "ds_read_b64_tr_b16 %2, %4 offset:256\n\t"
                     "ds_read_b64_tr_b16 %3, %4 offset:768"
                     : "=&v"(tr[kk*4+0]), "=&v"(tr[kk*4+1]),
                       "=&v"(tr[kk*4+2]), "=&v"(tr[kk*4+3])
                     : "v"(vb + kk*2048));
      }
    }

    if (__any(pm > m + 64.f)){            // T13 defer-max
      const float mn = fmaxf(m, pm);
      const float corr = exp2f((m - mn) * CEXP);
      m = mn;
      lsum *= corr;
      #pragma unroll
      for (int r = 0; r < 16; ++r){
        const int row = (r & 3) + 8*(r >> 2) + 4*(l >> 5);
        const float cr = __shfl(corr, row | (l & 32));
        o0[r] *= cr; o1[r] *= cr;
      }
    }
    #pragma unroll
    for (int r = 0; r < 16; ++r){
      const float p = exp2f((a0[r] - m) * CEXP);
      lsum += p;
      a0[r] = p;
    }

    // ---- wait V once, then PV: A-frag via cvt_pk + permlane32_swap
    asm volatile("s_waitcnt lgkmcnt(0)" ::: "memory");
    __builtin_amdgcn_sched_barrier(0);
    #pragma unroll
    for (int kk = 0; kk < 2; ++kk){
      const int o = kk * 8;
      const u32 x0 = pk2(a0[o+0], a0[o+1]);
      const u32 x1 = pk2(a0[o+2], a0[o+3]);
      const u32 y0 = pk2(a0[o+4], a0[o+5]);
      const u32 y1 = pk2(a0[o+6], a0[o+7]);
      const u32x2 r0v = __builtin_amdgcn_permlane32_swap(x0, y0, false, false);
      const u32x2 r1v = __builtin_amdgcn_permlane32_swap(x1, y1, false, false);
      union { u32 wd[4]; bf16x8 v; } af;
      af.wd[0] = r0v[0]; af.wd[1] = r1v[0]; af.wd[2] = r0v[1]; af.wd[3] = r1v[1];
      union { s16x4 hh[2]; bf16x8 v; } b0, b1;
      b0.hh[0] = tr[kk*4+0]; b0.hh[1] = tr[kk*4+1];
      b1.hh[0] = tr[kk*4+2]; b1.hh[1] = tr[kk*4+3];
      o0 = MFMA32(af.v, b0.v, o0);
      o1 = MFMA32(af.v, b1.v, o1);
    }

    cb3 = (cb3 == 2) ? 0 : cb3 + 1;
    vb2 ^= 1;
  }

  // ---- cross-half merge (once): __syncthreads drains all DMA before LDS reuse
  lsum += __shfl(lsum, l ^ 32);             // combine lane k-halves (same q)
  __syncthreads();
  float* const Osh  = (float*)smem;                         // 16 KB
  float2* const MLsh = (float2*)((char*)smem + 16384);      // 1 KB

  if (hr == 1){
    #pragma unroll
    for (int r = 0; r < 16; ++r){
      Osh[wr*2048 + l*32 + r]      = o0[r];
      Osh[wr*2048 + l*32 + 16 + r] = o1[r];
    }
    MLsh[wr*64 + l] = float2{m, lsum};
  }
  __syncthreads();

  if (hr == 0){
    const float2 ml1 = MLsh[wr*64 + l];
    const float mm = fmaxf(m, ml1.x);
    const float c0 = exp2f((m - mm) * CEXP);
    const float c1 = exp2f((ml1.x - mm) * CEXP);
    const float lm = lsum*c0 + ml1.y*c1;    // >0 always (half-0 non-empty)
    const float a0q = c0 / lm;
    const float a1q = c1 / lm;
    #pragma unroll
    for (int r = 0; r < 16; ++r){
      const int row = (r & 3) + 8*(r >> 2) + 4*(l >> 5);
      const float f0 = __shfl(a0q, row | (l & 32));
      const float f1 = __shfl(a1q, row | (l & 32));
      const int qg = q0 + row;
      u16* op = aout + (size_t)(b*SEQ + qg) * HIDDEN + h*64 + (l & 31);
      op[0]  = f2bf(o0[r]*f0 + Osh[wr*2048 + l*32 + r]*f1);
      op[32] = f2bf(o1[r]*f0 + Osh[wr*2048 + l*32 + 16 + r]*f1);
    }
  }
}

// ---------------- launch ----------------
extern "C" void kernel_launch(void* const* d_in, const int* in_sizes, int n_in,
                              void* d_out, int out_size, void* d_ws, size_t ws_size,
                              hipStream_t stream){
  const float* enc    = (const float*)d_in[0];
  const float* attn_w = (const float*)d_in[1];
  const float* attn_b = (const float*)d_in[2];
  const float* out_w  = (const float*)d_in[3];
  const float* out_b  = (const float*)d_in[4];

  char* ws = (char*)d_ws;
  u16* enc_bf = (u16*)(ws);
  u16* wa_bf  = (u16*)(ws + (size_t)( 8u << 20));
  u16* wo_bf  = (u16*)(ws + (size_t)(14u << 20));
  u16* qkv    = (u16*)(ws + (size_t)(16u << 20));
  u16* aout   = enc_bf;  // safe alias: attn runs strictly after GEMM1

  k_cvt3<<<dim3((CVT_N0+CVT_N1+CVT_N2 + 255)/256), 256, 0, stream>>>(
      enc, attn_w, out_w, enc_bf, wa_bf, wo_bf);

  k_gemm<QKVC,  true ><<<dim3(MROWS/128, QKVC/128),  256, 0, stream>>>(enc_bf, wa_bf, attn_b, qkv);
  k_attn<<<dim3(32, 32), 256, 0, stream>>>(qkv, aout);
  k_gemm<HIDDEN, false><<<dim3(MROWS/128, HIDDEN/128), 256, 0, stream>>>(aout, wo_bf, out_b, d_out);
}